// Round 1
// baseline (1963.808 us; speedup 1.0000x reference)
//
#include <hip/hip_runtime.h>
#include <hip/hip_bf16.h>

#define E_ 8
#define H_ 2048
#define I_ 5632
#define B_ 1024
#define K_ 2
#define NROWS (B_*K_)

#define BM 128
#define BN 128
#define BK 64

typedef __attribute__((ext_vector_type(8))) __bf16 bf16x8;
typedef __attribute__((ext_vector_type(4))) float f32x4;

union BF8 { __bf16 b[8]; uint4 q; };

__device__ __forceinline__ void gld_lds16(const void* g, void* l) {
  __builtin_amdgcn_global_load_lds(
      (const __attribute__((address_space(1))) void*)g,
      (__attribute__((address_space(3))) void*)l, 16, 0, 0);
}

// ---------------- phase 0: x (f32) -> xb (bf16) ----------------
__global__ void cvtx_kernel(const float* __restrict__ x, __bf16* __restrict__ xb) {
  int i = (blockIdx.x * 256 + threadIdx.x) * 8;
  float4 a = *(const float4*)(x + i);
  float4 b = *(const float4*)(x + i + 4);
  BF8 r;
  r.b[0] = (__bf16)a.x; r.b[1] = (__bf16)a.y; r.b[2] = (__bf16)a.z; r.b[3] = (__bf16)a.w;
  r.b[4] = (__bf16)b.x; r.b[5] = (__bf16)b.y; r.b[6] = (__bf16)b.z; r.b[7] = (__bf16)b.w;
  *(uint4*)(xb + i) = r.q;
}

// ---------------- phase 1: routing ----------------
__global__ void route_kernel(const int* __restrict__ ids,
                             int* __restrict__ counts, int* __restrict__ offsets,
                             int* __restrict__ tlist, int* __restrict__ row_of) {
  __shared__ int sc[E_], sp[E_], so[E_];
  int t = threadIdx.x;
  if (t < E_) { sc[t] = 0; sp[t] = 0; }
  __syncthreads();
  for (int idx = t; idx < NROWS; idx += 256) atomicAdd(&sc[ids[idx]], 1);
  __syncthreads();
  if (t == 0) { int acc = 0; for (int e = 0; e < E_; ++e) { so[e] = acc; acc += sc[e]; } }
  __syncthreads();
  for (int idx = t; idx < NROWS; idx += 256) {
    int e = ids[idx];
    int slot = atomicAdd(&sp[e], 1);
    int row = so[e] + slot;
    tlist[row] = idx / K_;
    row_of[idx] = row;
  }
  if (t < E_) { counts[t] = sc[t]; offsets[t] = so[t]; }
}

// ---------------- phase 2: gate+up dual GEMM + SiLU, act (bf16) ----------------
// A[row=token][k=h] bf16 (linear LDS, source pre-swizzled for conflict-free reads)
// Bg/Bu stored transposed: Bt[col=i][k=h] bf16, XOR-swizzled (slot ^= col&7)
__global__ __launch_bounds__(256, 2) void gateup_kernel(
    const __bf16* __restrict__ xb, const float* __restrict__ gw,
    const float* __restrict__ uw, const int* __restrict__ counts,
    const int* __restrict__ offsets, const int* __restrict__ tlist,
    __bf16* __restrict__ act)
{
  const int e = blockIdx.z;
  const int cnt = counts[e];
  const int m0 = blockIdx.x * BM;
  if (m0 >= cnt) return;
  const int off = offsets[e];
  const int n0 = blockIdx.y * BN;

  __shared__ __bf16 As[BM*BK];
  __shared__ __bf16 Bgs[BN*BK];
  __shared__ __bf16 Bus[BN*BK];

  const int tid  = threadIdx.x;
  const int lane = tid & 63;
  const int wave = tid >> 6;
  const int wr = (wave >> 1) * 64;
  const int wc = (wave & 1) * 64;

  // A staging precompute: 4 issues x 16B per thread; LDS linear, source slot swizzled
  const __bf16* asrc[4];
  __bf16* adst[4];
#pragma unroll
  for (int i = 0; i < 4; ++i) {
    int f = i*256 + tid;
    int r = f >> 3, cs = f & 7;
    int rr = m0 + r; if (rr >= cnt) rr = cnt - 1;
    int tok = tlist[off + rr];
    asrc[i] = xb + (size_t)tok * H_ + ((cs ^ (r & 7)) << 3);
    adst[i] = As + (size_t)f * 8;
  }

  // B staging: thread owns cols c0,c0+1 and k-rows kq*16..+15 (16 float2 loads/matrix)
  const int c0 = (tid & 63) * 2;
  const int kq = tid >> 6;  // 0..3
  const float* gsrc = gw + ((size_t)e*H_ + (size_t)kq*16)*I_ + n0 + c0;
  const float* usrc = uw + ((size_t)e*H_ + (size_t)kq*16)*I_ + n0 + c0;
  uint4* bgw[4]; uint4* buw[4];
#pragma unroll
  for (int cc = 0; cc < 2; ++cc) {
#pragma unroll
    for (int hh = 0; hh < 2; ++hh) {
      int c = c0 + cc;
      int s = kq*2 + hh;
      int byteoff = c*128 + ((s ^ (c & 7)) << 4);
      bgw[cc*2+hh] = (uint4*)((char*)Bgs + byteoff);
      buw[cc*2+hh] = (uint4*)((char*)Bus + byteoff);
    }
  }

  f32x4 accg[4][4], accu[4][4];
#pragma unroll
  for (int i = 0; i < 4; ++i)
#pragma unroll
    for (int j = 0; j < 4; ++j) {
      accg[i][j] = (f32x4){0.f,0.f,0.f,0.f};
      accu[i][j] = (f32x4){0.f,0.f,0.f,0.f};
    }

  for (int k0 = 0; k0 < H_; k0 += BK) {
#pragma unroll
    for (int i = 0; i < 4; ++i) gld_lds16(asrc[i] + k0, adst[i]);

    {
      float2 v[16];
#pragma unroll
      for (int kr = 0; kr < 16; ++kr)
        v[kr] = *(const float2*)(gsrc + (size_t)(k0 + kr) * I_);
#pragma unroll
      for (int cc = 0; cc < 2; ++cc)
#pragma unroll
        for (int hh = 0; hh < 2; ++hh) {
          BF8 p;
#pragma unroll
          for (int j = 0; j < 8; ++j) {
            float f = cc ? v[hh*8+j].y : v[hh*8+j].x;
            p.b[j] = (__bf16)f;
          }
          *bgw[cc*2+hh] = p.q;
        }
    }
    {
      float2 v[16];
#pragma unroll
      for (int kr = 0; kr < 16; ++kr)
        v[kr] = *(const float2*)(usrc + (size_t)(k0 + kr) * I_);
#pragma unroll
      for (int cc = 0; cc < 2; ++cc)
#pragma unroll
        for (int hh = 0; hh < 2; ++hh) {
          BF8 p;
#pragma unroll
          for (int j = 0; j < 8; ++j) {
            float f = cc ? v[hh*8+j].y : v[hh*8+j].x;
            p.b[j] = (__bf16)f;
          }
          *buw[cc*2+hh] = p.q;
        }
    }

    __syncthreads();

#pragma unroll
    for (int kk = 0; kk < 2; ++kk) {
      const int ks = kk*4 + (lane >> 4);
      bf16x8 a[4], bg[4], bu[4];
#pragma unroll
      for (int mi = 0; mi < 4; ++mi) {
        int row = wr + mi*16 + (lane & 15);
        a[mi] = *(const bf16x8*)((const char*)As + row*128 + ((ks ^ (row & 7)) << 4));
      }
#pragma unroll
      for (int ni = 0; ni < 4; ++ni) {
        int col = wc + ni*16 + (lane & 15);
        int sw = col*128 + ((ks ^ (col & 7)) << 4);
        bg[ni] = *(const bf16x8*)((const char*)Bgs + sw);
        bu[ni] = *(const bf16x8*)((const char*)Bus + sw);
      }
#pragma unroll
      for (int mi = 0; mi < 4; ++mi)
#pragma unroll
        for (int ni = 0; ni < 4; ++ni) {
          accg[mi][ni] = __builtin_amdgcn_mfma_f32_16x16x32_bf16(a[mi], bg[ni], accg[mi][ni], 0, 0, 0);
          accu[mi][ni] = __builtin_amdgcn_mfma_f32_16x16x32_bf16(a[mi], bu[ni], accu[mi][ni], 0, 0, 0);
        }
    }
    __syncthreads();
  }

  const int rsub = (lane >> 4) * 4;
  const int csub = lane & 15;
#pragma unroll
  for (int mi = 0; mi < 4; ++mi)
#pragma unroll
    for (int j = 0; j < 4; ++j) {
      int rl = wr + mi*16 + rsub + j;
      if (m0 + rl < cnt) {
        size_t orow = (size_t)(off + m0 + rl) * I_ + n0 + wc + csub;
#pragma unroll
        for (int ni = 0; ni < 4; ++ni) {
          float g = accg[mi][ni][j];
          float u = accu[mi][ni][j];
          float sg = g / (1.0f + __expf(-g));
          act[orow + ni*16] = (__bf16)(sg * u);
        }
      }
    }
}

// ---------------- phase 3: down GEMM -> rowbuf (f32) ----------------
__global__ __launch_bounds__(256, 2) void down_kernel(
    const __bf16* __restrict__ act, const float* __restrict__ dw,
    const int* __restrict__ counts, const int* __restrict__ offsets,
    float* __restrict__ rowbuf)
{
  const int e = blockIdx.z;
  const int cnt = counts[e];
  const int m0 = blockIdx.x * BM;
  if (m0 >= cnt) return;
  const int off = offsets[e];
  const int n0 = blockIdx.y * BN;

  __shared__ __bf16 As[BM*BK];
  __shared__ __bf16 Bs[BN*BK];

  const int tid  = threadIdx.x;
  const int lane = tid & 63;
  const int wave = tid >> 6;
  const int wr = (wave >> 1) * 64;
  const int wc = (wave & 1) * 64;

  const __bf16* asrc[4];
  __bf16* adst[4];
#pragma unroll
  for (int i = 0; i < 4; ++i) {
    int f = i*256 + tid;
    int r = f >> 3, cs = f & 7;
    int rr = m0 + r; if (rr >= cnt) rr = cnt - 1;
    asrc[i] = act + (size_t)(off + rr) * I_ + ((cs ^ (r & 7)) << 3);
    adst[i] = As + (size_t)f * 8;
  }

  const int c0 = (tid & 63) * 2;
  const int kq = tid >> 6;
  const float* dsrc = dw + ((size_t)e*I_ + (size_t)kq*16)*H_ + n0 + c0;
  uint4* bw[4];
#pragma unroll
  for (int cc = 0; cc < 2; ++cc)
#pragma unroll
    for (int hh = 0; hh < 2; ++hh) {
      int c = c0 + cc;
      int s = kq*2 + hh;
      bw[cc*2+hh] = (uint4*)((char*)Bs + c*128 + ((s ^ (c & 7)) << 4));
    }

  f32x4 acc[4][4];
#pragma unroll
  for (int i = 0; i < 4; ++i)
#pragma unroll
    for (int j = 0; j < 4; ++j) acc[i][j] = (f32x4){0.f,0.f,0.f,0.f};

  for (int k0 = 0; k0 < I_; k0 += BK) {
#pragma unroll
    for (int i = 0; i < 4; ++i) gld_lds16(asrc[i] + k0, adst[i]);

    {
      float2 v[16];
#pragma unroll
      for (int kr = 0; kr < 16; ++kr)
        v[kr] = *(const float2*)(dsrc + (size_t)(k0 + kr) * H_);
#pragma unroll
      for (int cc = 0; cc < 2; ++cc)
#pragma unroll
        for (int hh = 0; hh < 2; ++hh) {
          BF8 p;
#pragma unroll
          for (int j = 0; j < 8; ++j) {
            float f = cc ? v[hh*8+j].y : v[hh*8+j].x;
            p.b[j] = (__bf16)f;
          }
          *bw[cc*2+hh] = p.q;
        }
    }

    __syncthreads();

#pragma unroll
    for (int kk = 0; kk < 2; ++kk) {
      const int ks = kk*4 + (lane >> 4);
      bf16x8 a[4], b[4];
#pragma unroll
      for (int mi = 0; mi < 4; ++mi) {
        int row = wr + mi*16 + (lane & 15);
        a[mi] = *(const bf16x8*)((const char*)As + row*128 + ((ks ^ (row & 7)) << 4));
      }
#pragma unroll
      for (int ni = 0; ni < 4; ++ni) {
        int col = wc + ni*16 + (lane & 15);
        b[ni] = *(const bf16x8*)((const char*)Bs + col*128 + ((ks ^ (col & 7)) << 4));
      }
#pragma unroll
      for (int mi = 0; mi < 4; ++mi)
#pragma unroll
        for (int ni = 0; ni < 4; ++ni)
          acc[mi][ni] = __builtin_amdgcn_mfma_f32_16x16x32_bf16(a[mi], b[ni], acc[mi][ni], 0, 0, 0);
    }
    __syncthreads();
  }

  const int rsub = (lane >> 4) * 4;
  const int csub = lane & 15;
#pragma unroll
  for (int mi = 0; mi < 4; ++mi)
#pragma unroll
    for (int j = 0; j < 4; ++j) {
      int rl = wr + mi*16 + rsub + j;
      if (m0 + rl < cnt) {
        size_t orow = (size_t)(off + m0 + rl) * H_ + n0 + wc + csub;
#pragma unroll
        for (int ni = 0; ni < 4; ++ni)
          rowbuf[orow + ni*16] = acc[mi][ni][j];
      }
    }
}

// ---------------- phase 4: weighted combine ----------------
__global__ void combine_kernel(const float* __restrict__ ew, const int* __restrict__ row_of,
                               const float* __restrict__ rowbuf, float* __restrict__ out) {
  int idx = blockIdx.x * 256 + threadIdx.x;   // over B_*H_/4
  int t  = idx >> 9;                          // H_/4 = 512
  int h4 = idx & 511;
  float w0 = ew[t*2+0], w1 = ew[t*2+1];
  int r0 = row_of[t*2+0], r1 = row_of[t*2+1];
  float4 a = *(const float4*)(rowbuf + (size_t)r0*H_ + h4*4);
  float4 b = *(const float4*)(rowbuf + (size_t)r1*H_ + h4*4);
  float4 o;
  o.x = w0*a.x + w1*b.x; o.y = w0*a.y + w1*b.y;
  o.z = w0*a.z + w1*b.z; o.w = w0*a.w + w1*b.w;
  *(float4*)(out + (size_t)idx*4) = o;
}

extern "C" void kernel_launch(void* const* d_in, const int* in_sizes, int n_in,
                              void* d_out, int out_size, void* d_ws, size_t ws_size,
                              hipStream_t stream) {
  const float* x   = (const float*)d_in[0];
  const int*   ids = (const int*)d_in[1];
  const float* ew  = (const float*)d_in[2];
  const float* gw  = (const float*)d_in[3];
  const float* uw  = (const float*)d_in[4];
  const float* dwn = (const float*)d_in[5];
  float* out = (float*)d_out;

  char* ws = (char*)d_ws;
  int* counts  = (int*)ws;          // 8
  int* offsets = counts + 8;        // 8
  int* tlist   = offsets + 8;       // NROWS
  int* row_of  = tlist + NROWS;     // NROWS
  __bf16* xb   = (__bf16*)(ws + 32768);
  __bf16* act  = (__bf16*)(ws + 32768 + (size_t)B_*H_*2);
  float* rowbuf = (float*)(ws + 32768 + (size_t)B_*H_*2 + (size_t)NROWS*I_*2);

  cvtx_kernel<<<B_*H_/(256*8), 256, 0, stream>>>(x, xb);
  route_kernel<<<1, 256, 0, stream>>>(ids, counts, offsets, tlist, row_of);

  dim3 g2(16, I_/BN, E_);   // m-tiles innermost -> LLC reuse of weight tiles
  gateup_kernel<<<g2, 256, 0, stream>>>(xb, gw, uw, counts, offsets, tlist, act);

  dim3 g3(16, H_/BN, E_);
  down_kernel<<<g3, 256, 0, stream>>>(act, dwn, counts, offsets, rowbuf);

  combine_kernel<<<(B_*H_/4)/256, 256, 0, stream>>>(ew, row_of, rowbuf, out);
}

// Round 2
// 530.086 us; speedup vs baseline: 3.7047x; 3.7047x over previous
//
#include <hip/hip_runtime.h>
#include <hip/hip_bf16.h>

#define E_ 8
#define H_ 2048
#define I_ 5632
#define B_ 1024
#define K_ 2
#define NROWS (B_*K_)

#define BM 128
#define BN 128
#define BK 64
#define MAXT 24   // Σ_e ceil(cnt_e/BM) <= NROWS/BM + E = 16+8 = 24

typedef __attribute__((ext_vector_type(8))) __bf16 bf16x8;
typedef __attribute__((ext_vector_type(4))) float f32x4;

union BF8 { __bf16 b[8]; uint4 q; };

__device__ __forceinline__ void gld_lds16(const void* g, void* l) {
  __builtin_amdgcn_global_load_lds(
      (const __attribute__((address_space(1))) void*)g,
      (__attribute__((address_space(3))) void*)l, 16, 0, 0);
}

// ---------------- phase 0: x (f32) -> xb (bf16) ----------------
__global__ void cvtx_kernel(const float* __restrict__ x, __bf16* __restrict__ xb) {
  int i = (blockIdx.x * 256 + threadIdx.x) * 8;
  float4 a = *(const float4*)(x + i);
  float4 b = *(const float4*)(x + i + 4);
  BF8 r;
  r.b[0] = (__bf16)a.x; r.b[1] = (__bf16)a.y; r.b[2] = (__bf16)a.z; r.b[3] = (__bf16)a.w;
  r.b[4] = (__bf16)b.x; r.b[5] = (__bf16)b.y; r.b[6] = (__bf16)b.z; r.b[7] = (__bf16)b.w;
  *(uint4*)(xb + i) = r.q;
}

// ---------------- phase 1: routing + dense tile list ----------------
__global__ void route_kernel(const int* __restrict__ ids,
                             int* __restrict__ counts, int* __restrict__ offsets,
                             int* __restrict__ tlist, int* __restrict__ row_of,
                             int* __restrict__ tile_e, int* __restrict__ tile_m) {
  __shared__ int sc[E_], sp[E_], so[E_];
  int t = threadIdx.x;
  if (t < E_) { sc[t] = 0; sp[t] = 0; }
  __syncthreads();
  for (int idx = t; idx < NROWS; idx += 256) atomicAdd(&sc[ids[idx]], 1);
  __syncthreads();
  if (t == 0) {
    int acc = 0;
    for (int e = 0; e < E_; ++e) { so[e] = acc; acc += sc[e]; }
    // dense tile list: (expert, m0) pairs, padded with m0=INT_MAX
    int nt = 0;
    for (int e = 0; e < E_; ++e)
      for (int m0 = 0; m0 < sc[e]; m0 += BM) { tile_e[nt] = e; tile_m[nt] = m0; ++nt; }
    for (; nt < MAXT; ++nt) { tile_e[nt] = 0; tile_m[nt] = 0x7FFFFFFF; }
  }
  __syncthreads();
  for (int idx = t; idx < NROWS; idx += 256) {
    int e = ids[idx];
    int slot = atomicAdd(&sp[e], 1);
    int row = so[e] + slot;
    tlist[row] = idx / K_;
    row_of[idx] = row;
  }
  if (t < E_) { counts[t] = sc[t]; offsets[t] = so[t]; }
}

// ---------------- phase 2: gate+up dual GEMM + SiLU, act (bf16) ----------------
// Dense 1-D grid of MAXT*44 blocks. Work w enumerated (n-col major, tile minor)
// so m-tiles sharing a weight tile are 8 apart in block id -> same XCD.
__global__ __launch_bounds__(256, 2) void gateup_kernel(
    const __bf16* __restrict__ xb, const float* __restrict__ gw,
    const float* __restrict__ uw, const int* __restrict__ counts,
    const int* __restrict__ offsets, const int* __restrict__ tlist,
    const int* __restrict__ tile_e, const int* __restrict__ tile_m,
    __bf16* __restrict__ act)
{
  const int id = blockIdx.x;                    // [0, 1056)
  const int w  = (id & 7) * 132 + (id >> 3);    // bijection, pairs stay on one XCD
  const int tt = w % MAXT;
  const int ny = w / MAXT;                      // [0, 44)
  const int e  = tile_e[tt];
  const int m0 = tile_m[tt];
  const int cnt = counts[e];
  if (m0 >= cnt) return;
  const int off = offsets[e];
  const int n0 = ny * BN;

  __shared__ __bf16 As[BM*BK];
  __shared__ __bf16 Bgs[BN*BK];
  __shared__ __bf16 Bus[BN*BK];

  const int tid  = threadIdx.x;
  const int lane = tid & 63;
  const int wave = tid >> 6;
  const int wr = (wave >> 1) * 64;
  const int wc = (wave & 1) * 64;

  // A staging: 4 issues x 16B per thread; LDS linear, source slot swizzled
  const __bf16* asrc[4];
  __bf16* adst[4];
#pragma unroll
  for (int i = 0; i < 4; ++i) {
    int f = i*256 + tid;
    int r = f >> 3, cs = f & 7;
    int rr = m0 + r; if (rr >= cnt) rr = cnt - 1;
    int tok = tlist[off + rr];
    asrc[i] = xb + (size_t)tok * H_ + ((cs ^ (r & 7)) << 3);
    adst[i] = As + (size_t)f * 8;
  }

  // B staging: thread owns cols c0,c0+1 and k-rows kq*16..+15
  const int c0 = (tid & 63) * 2;
  const int kq = tid >> 6;  // 0..3
  const float* gsrc = gw + ((size_t)e*H_ + (size_t)kq*16)*I_ + n0 + c0;
  const float* usrc = uw + ((size_t)e*H_ + (size_t)kq*16)*I_ + n0 + c0;
  uint4* bgw[4]; uint4* buw[4];
#pragma unroll
  for (int cc = 0; cc < 2; ++cc) {
#pragma unroll
    for (int hh = 0; hh < 2; ++hh) {
      int c = c0 + cc;
      int s = kq*2 + hh;
      int byteoff = c*128 + ((s ^ (c & 7)) << 4);
      bgw[cc*2+hh] = (uint4*)((char*)Bgs + byteoff);
      buw[cc*2+hh] = (uint4*)((char*)Bus + byteoff);
    }
  }

  f32x4 accg[4][4], accu[4][4];
#pragma unroll
  for (int i = 0; i < 4; ++i)
#pragma unroll
    for (int j = 0; j < 4; ++j) {
      accg[i][j] = (f32x4){0.f,0.f,0.f,0.f};
      accu[i][j] = (f32x4){0.f,0.f,0.f,0.f};
    }

  for (int k0 = 0; k0 < H_; k0 += BK) {
#pragma unroll
    for (int i = 0; i < 4; ++i) gld_lds16(asrc[i] + k0, adst[i]);

    // merged g+u load batch: 32 loads in flight
    float2 vg[16], vu[16];
#pragma unroll
    for (int kr = 0; kr < 16; ++kr)
      vg[kr] = *(const float2*)(gsrc + (size_t)(k0 + kr) * I_);
#pragma unroll
    for (int kr = 0; kr < 16; ++kr)
      vu[kr] = *(const float2*)(usrc + (size_t)(k0 + kr) * I_);

#pragma unroll
    for (int cc = 0; cc < 2; ++cc)
#pragma unroll
      for (int hh = 0; hh < 2; ++hh) {
        BF8 pg, pu;
#pragma unroll
        for (int j = 0; j < 8; ++j) {
          pg.b[j] = (__bf16)(cc ? vg[hh*8+j].y : vg[hh*8+j].x);
          pu.b[j] = (__bf16)(cc ? vu[hh*8+j].y : vu[hh*8+j].x);
        }
        *bgw[cc*2+hh] = pg.q;
        *buw[cc*2+hh] = pu.q;
      }

    __syncthreads();

#pragma unroll
    for (int kk = 0; kk < 2; ++kk) {
      const int ks = kk*4 + (lane >> 4);
      bf16x8 a[4], bg[4], bu[4];
#pragma unroll
      for (int mi = 0; mi < 4; ++mi) {
        int row = wr + mi*16 + (lane & 15);
        a[mi] = *(const bf16x8*)((const char*)As + row*128 + ((ks ^ (row & 7)) << 4));
      }
#pragma unroll
      for (int ni = 0; ni < 4; ++ni) {
        int col = wc + ni*16 + (lane & 15);
        int sw = col*128 + ((ks ^ (col & 7)) << 4);
        bg[ni] = *(const bf16x8*)((const char*)Bgs + sw);
        bu[ni] = *(const bf16x8*)((const char*)Bus + sw);
      }
#pragma unroll
      for (int mi = 0; mi < 4; ++mi)
#pragma unroll
        for (int ni = 0; ni < 4; ++ni) {
          accg[mi][ni] = __builtin_amdgcn_mfma_f32_16x16x32_bf16(a[mi], bg[ni], accg[mi][ni], 0, 0, 0);
          accu[mi][ni] = __builtin_amdgcn_mfma_f32_16x16x32_bf16(a[mi], bu[ni], accu[mi][ni], 0, 0, 0);
        }
    }
    __syncthreads();
  }

  const int rsub = (lane >> 4) * 4;
  const int csub = lane & 15;
#pragma unroll
  for (int mi = 0; mi < 4; ++mi)
#pragma unroll
    for (int j = 0; j < 4; ++j) {
      int rl = wr + mi*16 + rsub + j;
      if (m0 + rl < cnt) {
        size_t orow = (size_t)(off + m0 + rl) * I_ + n0 + wc + csub;
#pragma unroll
        for (int ni = 0; ni < 4; ++ni) {
          float g = accg[mi][ni][j];
          float u = accu[mi][ni][j];
          float sg = g / (1.0f + __expf(-g));
          act[orow + ni*16] = (__bf16)(sg * u);
        }
      }
    }
}

// ---------------- phase 3: down GEMM -> rowbuf (f32) ----------------
__global__ __launch_bounds__(256, 2) void down_kernel(
    const __bf16* __restrict__ act, const float* __restrict__ dw,
    const int* __restrict__ counts, const int* __restrict__ offsets,
    const int* __restrict__ tile_e, const int* __restrict__ tile_m,
    float* __restrict__ rowbuf)
{
  const int id = blockIdx.x;                    // [0, 384)
  const int w  = (id & 7) * 48 + (id >> 3);
  const int tt = w % MAXT;
  const int ny = w / MAXT;                      // [0, 16)
  const int e  = tile_e[tt];
  const int m0 = tile_m[tt];
  const int cnt = counts[e];
  if (m0 >= cnt) return;
  const int off = offsets[e];
  const int n0 = ny * BN;

  __shared__ __bf16 As[BM*BK];
  __shared__ __bf16 Bs[BN*BK];

  const int tid  = threadIdx.x;
  const int lane = tid & 63;
  const int wave = tid >> 6;
  const int wr = (wave >> 1) * 64;
  const int wc = (wave & 1) * 64;

  const __bf16* asrc[4];
  __bf16* adst[4];
#pragma unroll
  for (int i = 0; i < 4; ++i) {
    int f = i*256 + tid;
    int r = f >> 3, cs = f & 7;
    int rr = m0 + r; if (rr >= cnt) rr = cnt - 1;
    asrc[i] = act + (size_t)(off + rr) * I_ + ((cs ^ (r & 7)) << 3);
    adst[i] = As + (size_t)f * 8;
  }

  const int c0 = (tid & 63) * 2;
  const int kq = tid >> 6;
  const float* dsrc = dw + ((size_t)e*I_ + (size_t)kq*16)*H_ + n0 + c0;
  uint4* bw[4];
#pragma unroll
  for (int cc = 0; cc < 2; ++cc)
#pragma unroll
    for (int hh = 0; hh < 2; ++hh) {
      int c = c0 + cc;
      int s = kq*2 + hh;
      bw[cc*2+hh] = (uint4*)((char*)Bs + c*128 + ((s ^ (c & 7)) << 4));
    }

  f32x4 acc[4][4];
#pragma unroll
  for (int i = 0; i < 4; ++i)
#pragma unroll
    for (int j = 0; j < 4; ++j) acc[i][j] = (f32x4){0.f,0.f,0.f,0.f};

  for (int k0 = 0; k0 < I_; k0 += BK) {
#pragma unroll
    for (int i = 0; i < 4; ++i) gld_lds16(asrc[i] + k0, adst[i]);

    {
      float2 v[16];
#pragma unroll
      for (int kr = 0; kr < 16; ++kr)
        v[kr] = *(const float2*)(dsrc + (size_t)(k0 + kr) * H_);
#pragma unroll
      for (int cc = 0; cc < 2; ++cc)
#pragma unroll
        for (int hh = 0; hh < 2; ++hh) {
          BF8 p;
#pragma unroll
          for (int j = 0; j < 8; ++j)
            p.b[j] = (__bf16)(cc ? v[hh*8+j].y : v[hh*8+j].x);
          *bw[cc*2+hh] = p.q;
        }
    }

    __syncthreads();

#pragma unroll
    for (int kk = 0; kk < 2; ++kk) {
      const int ks = kk*4 + (lane >> 4);
      bf16x8 a[4], b[4];
#pragma unroll
      for (int mi = 0; mi < 4; ++mi) {
        int row = wr + mi*16 + (lane & 15);
        a[mi] = *(const bf16x8*)((const char*)As + row*128 + ((ks ^ (row & 7)) << 4));
      }
#pragma unroll
      for (int ni = 0; ni < 4; ++ni) {
        int col = wc + ni*16 + (lane & 15);
        b[ni] = *(const bf16x8*)((const char*)Bs + col*128 + ((ks ^ (col & 7)) << 4));
      }
#pragma unroll
      for (int mi = 0; mi < 4; ++mi)
#pragma unroll
        for (int ni = 0; ni < 4; ++ni)
          acc[mi][ni] = __builtin_amdgcn_mfma_f32_16x16x32_bf16(a[mi], b[ni], acc[mi][ni], 0, 0, 0);
    }
    __syncthreads();
  }

  const int rsub = (lane >> 4) * 4;
  const int csub = lane & 15;
#pragma unroll
  for (int mi = 0; mi < 4; ++mi)
#pragma unroll
    for (int j = 0; j < 4; ++j) {
      int rl = wr + mi*16 + rsub + j;
      if (m0 + rl < cnt) {
        size_t orow = (size_t)(off + m0 + rl) * H_ + n0 + wc + csub;
#pragma unroll
        for (int ni = 0; ni < 4; ++ni)
          rowbuf[orow + ni*16] = acc[mi][ni][j];
      }
    }
}

// ---------------- phase 4: weighted combine ----------------
__global__ void combine_kernel(const float* __restrict__ ew, const int* __restrict__ row_of,
                               const float* __restrict__ rowbuf, float* __restrict__ out) {
  int idx = blockIdx.x * 256 + threadIdx.x;   // over B_*H_/4
  int t  = idx >> 9;                          // H_/4 = 512
  int h4 = idx & 511;
  float w0 = ew[t*2+0], w1 = ew[t*2+1];
  int r0 = row_of[t*2+0], r1 = row_of[t*2+1];
  float4 a = *(const float4*)(rowbuf + (size_t)r0*H_ + h4*4);
  float4 b = *(const float4*)(rowbuf + (size_t)r1*H_ + h4*4);
  float4 o;
  o.x = w0*a.x + w1*b.x; o.y = w0*a.y + w1*b.y;
  o.z = w0*a.z + w1*b.z; o.w = w0*a.w + w1*b.w;
  *(float4*)(out + (size_t)idx*4) = o;
}

extern "C" void kernel_launch(void* const* d_in, const int* in_sizes, int n_in,
                              void* d_out, int out_size, void* d_ws, size_t ws_size,
                              hipStream_t stream) {
  const float* x   = (const float*)d_in[0];
  const int*   ids = (const int*)d_in[1];
  const float* ew  = (const float*)d_in[2];
  const float* gw  = (const float*)d_in[3];
  const float* uw  = (const float*)d_in[4];
  const float* dwn = (const float*)d_in[5];
  float* out = (float*)d_out;

  char* ws = (char*)d_ws;
  int* counts  = (int*)ws;          // 8
  int* offsets = counts + 8;        // 8
  int* tlist   = offsets + 8;       // NROWS
  int* row_of  = tlist + NROWS;     // NROWS
  int* tile_e  = row_of + NROWS;    // MAXT
  int* tile_m  = tile_e + MAXT;     // MAXT
  __bf16* xb   = (__bf16*)(ws + 32768);
  __bf16* act  = (__bf16*)(ws + 32768 + (size_t)B_*H_*2);
  float* rowbuf = (float*)(ws + 32768 + (size_t)B_*H_*2 + (size_t)NROWS*I_*2);

  cvtx_kernel<<<B_*H_/(256*8), 256, 0, stream>>>(x, xb);
  route_kernel<<<1, 256, 0, stream>>>(ids, counts, offsets, tlist, row_of, tile_e, tile_m);

  gateup_kernel<<<MAXT*(I_/BN), 256, 0, stream>>>(xb, gw, uw, counts, offsets, tlist,
                                                  tile_e, tile_m, act);

  down_kernel<<<MAXT*(H_/BN), 256, 0, stream>>>(act, dwn, counts, offsets,
                                                tile_e, tile_m, rowbuf);

  combine_kernel<<<(B_*H_/4)/256, 256, 0, stream>>>(ew, row_of, rowbuf, out);
}